// Round 4
// baseline (12185.907 us; speedup 1.0000x reference)
//
#include <hip/hip_runtime.h>
#include <hip/hip_bf16.h>

#define TLEN 65536
#define NSEQ 32
#define MAXD 10000

__device__ __forceinline__ float rl(float v, int l) {
    return __uint_as_float(__builtin_amdgcn_readlane(__float_as_uint(v), l));
}
__device__ __forceinline__ float rcp_(float x) { return __builtin_amdgcn_rcpf(x); }
__device__ __forceinline__ float ex2_(float x) { return __builtin_amdgcn_exp2f(x); }

// ---------------------------------------------------------------------------
// GRU: one sequence per wave, lanes 0-7 only (lane j owns hidden unit j);
// lanes 8-63 exit immediately. h broadcast via v_readlane -> SGPRs.
// Weights pre-scaled by -log2(e) (r,z) and 2*log2(e) (n) so the sigmoid/tanh
// paths need no constant muls on the recurrence chain.
// Update: h' = A + u*(2z-2) with A = 1+z*(h-1) (off-chain) -> one fma after
// the n-path rcp. pre_d staged into a rotating VGPR slot via predicated
// select (s is lane-uniform; masks hoisted), stored 8-wide every 8 steps.
// ---------------------------------------------------------------------------
__global__ __launch_bounds__(64, 1) void gru_kernel(
    const float* __restrict__ x,      // (NSEQ, TLEN)
    const float* __restrict__ w_ih,   // (24, 1)
    const float* __restrict__ w_hh,   // (24, 8) row-major
    const float* __restrict__ b_ih,   // (24,)
    const float* __restrict__ b_hh,   // (24,)
    const float* __restrict__ w_out,  // (1, 8)
    float* __restrict__ pre_d)        // (NSEQ, TLEN)
{
    const int lane = threadIdx.x & 63;
    if (lane >= 8) return;            // only lanes 0-7 do work
    const int j   = lane;
    const int seq = blockIdx.x;

    const float L2E = 1.44269504088896f;
    const float NEG = -L2E, POS2 = 2.0f * L2E;

    float whr[8], whz[8], whn[8], wov[8];
#pragma unroll
    for (int k = 0; k < 8; ++k) {
        whr[k] = NEG  * w_hh[(0  + j) * 8 + k];
        whz[k] = NEG  * w_hh[(8  + j) * 8 + k];
        whn[k] = POS2 * w_hh[(16 + j) * 8 + k];
        wov[k] = w_out[k];
    }
    const float wir = NEG  * w_ih[j];
    const float wiz = NEG  * w_ih[8 + j];
    const float win = POS2 * w_ih[16 + j];
    const float br  = NEG  * (b_ih[j]     + b_hh[j]);
    const float bz  = NEG  * (b_ih[8 + j] + b_hh[8 + j]);
    const float bni = POS2 * b_ih[16 + j];
    const float bnh = POS2 * b_hh[16 + j];

    const float*  xs  = x     + (size_t)seq * TLEN;
    float*        pd  = pre_d + (size_t)seq * TLEN;
    const float4* xs4 = (const float4*)xs;

    float h   = 0.0f;
    float vst = 0.0f;                 // pre_d staging (slot = (t-1)&7)

    const int NCH = TLEN / 16;
    float4 a0 = xs4[0], a1 = xs4[1], a2 = xs4[2], a3 = xs4[3];

    for (int c = 0; c < NCH; ++c) {
        const int cn = (c + 1 < NCH) ? (c + 1) : c;
        float4 b0 = xs4[cn * 4 + 0], b1 = xs4[cn * 4 + 1];
        float4 b2 = xs4[cn * 4 + 2], b3 = xs4[cn * 4 + 3];

        float cx[16];
        cx[0]=a0.x; cx[1]=a0.y; cx[2]=a0.z; cx[3]=a0.w;
        cx[4]=a1.x; cx[5]=a1.y; cx[6]=a1.z; cx[7]=a1.w;
        cx[8]=a2.x; cx[9]=a2.y; cx[10]=a2.z; cx[11]=a2.w;
        cx[12]=a3.x; cx[13]=a3.y; cx[14]=a3.z; cx[15]=a3.w;

#pragma unroll
        for (int u = 0; u < 16; ++u) {
            const int t = c * 16 + u;

            // broadcast h_{t-1} to SGPRs
            float hu[8];
#pragma unroll
            for (int k = 0; k < 8; ++k) hu[k] = rl(h, k);

            // deferred pre_d[t-1] = h_{t-1} . w_out  (off-chain; lane-uniform)
            float s = hu[0] * wov[0];
#pragma unroll
            for (int k = 1; k < 8; ++k) s = fmaf(hu[k], wov[k], s);
            if (t > 0) {
                const int slot = (u - 1) & 7;           // == (t-1)&7
                vst = (lane == slot) ? s : vst;         // hoisted mask + cndmask
            }
            if ((u == 8) || (u == 0 && c > 0)) pd[t - 8 + lane] = vst;

            // gate pre-activations (weights pre-scaled; two 4-fma chains each)
            const float xt = cx[u];
            float arA = fmaf(xt, wir, br),  arB = 0.0f;
            float azA = fmaf(xt, wiz, bz),  azB = 0.0f;
            const float gn = fmaf(xt, win, bni);
            float anA = bnh,                anB = 0.0f;
#pragma unroll
            for (int k = 0; k < 4; ++k) {
                arA = fmaf(whr[k], hu[k], arA);
                azA = fmaf(whz[k], hu[k], azA);
                anA = fmaf(whn[k], hu[k], anA);
            }
#pragma unroll
            for (int k = 4; k < 8; ++k) {
                arB = fmaf(whr[k], hu[k], arB);
                azB = fmaf(whz[k], hu[k], azB);
                anB = fmaf(whn[k], hu[k], anB);
            }
            const float ar = arA + arB;
            const float az = azA + azB;
            const float an = anA + anB;

            // r = sigmoid, z = sigmoid (args already *(-log2e))
            const float r  = rcp_(1.0f + ex2_(ar));
            const float z  = rcp_(1.0f + ex2_(az));
            // n-path: u_ = 1/(1+e^{2nv}) (arg already *(2log2e)); n = 1-2u_
            const float nv = fmaf(r, an, gn);
            const float u_ = rcp_(1.0f + ex2_(nv));
            // h' = (1-z)n + zh = A + u_*(2z-2),  A = 1 + z*(h-1)   (off-chain)
            const float A   = fmaf(z, h - 1.0f, 1.0f);
            const float zm2 = fmaf(2.0f, z, -2.0f);
            h = fmaf(u_, zm2, A);
        }
        a0 = b0; a1 = b1; a2 = b2; a3 = b3;
    }

    // tail: pre_d[TLEN-1] from final h; flush last 8 slots
    {
        float hu[8];
#pragma unroll
        for (int k = 0; k < 8; ++k) hu[k] = rl(h, k);
        float s = hu[0] * wov[0];
#pragma unroll
        for (int k = 1; k < 8; ++k) s = fmaf(hu[k], wov[k], s);
        vst = (lane == 7) ? s : vst;
        pd[TLEN - 8 + lane] = vst;
    }
}

// ---------------------------------------------------------------------------
// Kernel 2: time-varying fractional delay (2-tap gather). Fully parallel.
// ---------------------------------------------------------------------------
__global__ void delay_kernel(
    const float* __restrict__ pre_d,  // (NSEQ, TLEN)
    const float* __restrict__ dt,     // (NSEQ, TLEN)
    const float* __restrict__ buffer, // (NSEQ, MAXD) -- zeros from setup
    float* __restrict__ y)            // (NSEQ, TLEN)
{
    const int idx = blockIdx.x * blockDim.x + threadIdx.x;
    if (idx >= NSEQ * TLEN) return;
    const int n = idx >> 16;          // TLEN == 2^16
    const int t = idx & (TLEN - 1);

    const float d  = dt[idx];
    const float p  = (float)MAXD - d;       // fractional tap position
    const float k0 = floorf(p);
    const float frac = p - k0;              // w1
    const float w0 = 1.0f - frac;

    const int k0i = (int)k0;
    const int k1i = min(k0i + 1, MAXD);
    const int i0 = t + k0i - MAXD;          // index into pre_d (may be <0)
    const int i1 = t + k1i - MAXD;

    const float* pdn  = pre_d  + (size_t)n * TLEN;
    const float* bufn = buffer + (size_t)n * MAXD;

    const float y0 = (i0 >= 0) ? pdn[i0] : bufn[t + k0i];
    const float y1 = (i1 >= 0) ? pdn[i1] : bufn[t + k1i];

    y[idx] = fmaf(w0, y0, frac * y1);
}

extern "C" void kernel_launch(void* const* d_in, const int* in_sizes, int n_in,
                              void* d_out, int out_size, void* d_ws, size_t ws_size,
                              hipStream_t stream) {
    const float* x      = (const float*)d_in[0];
    const float* dtraj  = (const float*)d_in[1];
    const float* buffer = (const float*)d_in[2];
    const float* w_ih   = (const float*)d_in[3];
    const float* w_hh   = (const float*)d_in[4];
    const float* b_ih   = (const float*)d_in[5];
    const float* b_hh   = (const float*)d_in[6];
    const float* w_out  = (const float*)d_in[7];

    float* y     = (float*)d_out;                       // output 0: (32,1,65536)
    float* pre_d = (float*)d_out + (size_t)NSEQ * TLEN; // output 1

    // GRU: one sequence per wave -> 32 blocks x 64 threads
    gru_kernel<<<dim3(NSEQ), dim3(64), 0, stream>>>(x, w_ih, w_hh, b_ih, b_hh,
                                                    w_out, pre_d);

    // Delay line: one thread per (n, t)
    const int total = NSEQ * TLEN;
    delay_kernel<<<dim3((total + 255) / 256), dim3(256), 0, stream>>>(
        pre_d, dtraj, buffer, y);
}